// Round 1
// baseline (228.549 us; speedup 1.0000x reference)
//
#include <hip/hip_runtime.h>

// HistogramLoss: two [32,3,512,512] fp32 inputs, per-(B,C) 64-bin histogram
// over [0,1], row-normalized (row count exactly 2^18), L1 mean of diff.
//
// R6: bit-sliced carry-save histogram in VGPRs. R5 (fire-and-forget
// ds_add_u32) ran at ~1 elem/cy/CU = 80us with ALL pipe counters idle ->
// the LDS atomic unit itself is the serial resource (~1 lane-op/cy/CU);
// banking/pitch tricks can't help. Here the inner loop touches NO memory:
// each thread keeps 8 u64 bit-planes (bit b of plane k = bit k of count
// for bin b), and each element's one-hot (1ull<<bin) is added via a 4:2
// carry-save compressor per float4 (~84 VALU instr / 4 elems). Max count
// per (thread,bin) = 128 = exactly representable in 8 planes -> exact,
// single flush. Flush: per (bin,plane) __ballot+__popcll gives the
// wave-sum directly (scalar pipe), so the ONLY LDS op in the whole kernel
// is one ds_add per lane per wave (4 wave-ops/block vs 2048 in R5).
// Predicted: VALU-bound ~20us + memory ~20-25us overlapped -> 30-40us.

#define HW        262144             // 512*512 = 2^18
#define ROWS      96                 // B*C per image
#define NBINS     64
#define BPR       8                  // blocks per row
#define CHUNK     (HW / BPR)         // 32768 elements per block
#define THREADS   256
#define F4_ITERS  (CHUNK / 4 / THREADS)  // 32 float4 per thread -> 128 elems
#define NBLOCKS   (2 * ROWS * BPR)   // 1536 (6 blocks/CU)

typedef unsigned long long u64;

__global__ __launch_bounds__(THREADS)
void hist_kernel(const float* __restrict__ fake,
                 const float* __restrict__ real,
                 unsigned int* __restrict__ partial) {
    __shared__ unsigned int bhist[NBINS];

    const int tid  = threadIdx.x;
    const int lane = tid & 63;

    if (tid < NBINS) bhist[tid] = 0u;
    __syncthreads();

    const int b     = blockIdx.x;          // 0 .. 1535
    const int chunk = b & (BPR - 1);
    const int rowg  = b >> 3;              // 0..191: img*ROWS + row
    const float* src = (rowg < ROWS) ? fake : real;
    const int row    = (rowg < ROWS) ? rowg : (rowg - ROWS);

    const float4* __restrict__ p =
        (const float4*)(src + (size_t)row * HW + (size_t)chunk * CHUNK);

    // 8 bit-planes: bit bb of pk = bit k of this thread's count for bin bb.
    // Named scalars (NOT an array) so they stay in VGPRs (no scratch).
    u64 p0 = 0, p1 = 0, p2 = 0, p3 = 0, p4 = 0, p5 = 0, p6 = 0, p7 = 0;

#pragma unroll 4
    for (int i = 0; i < F4_ITERS; ++i) {
        float4 v = p[i * THREADS + tid];
        int b0 = min((int)(v.x * 64.0f), 63);
        int b1 = min((int)(v.y * 64.0f), 63);
        int b2 = min((int)(v.z * 64.0f), 63);
        int b3 = min((int)(v.w * 64.0f), 63);
        u64 m0 = 1ull << b0, m1 = 1ull << b1;
        u64 m2 = 1ull << b2, m3 = 1ull << b3;

        // 4:2 compress the four one-hots at weight 1:
        //   S = weight-1 sum; c1,c2,C = weight-2 terms
        u64 s1 = m0 ^ m1, c1 = m0 & m1;
        u64 s2 = m2 ^ m3, c2 = m2 & m3;
        u64 S  = s1 ^ s2, C  = s1 & s2;

        // plane0 += S  (carry g0 out at weight 2)
        u64 g0 = p0 & S;  p0 ^= S;

        // weight-2 terms now: c1, c2, C, g0.
        // CSA3(c1,c2,C) -> s3 (w2) + t3 (w4)
        u64 u  = c1 ^ c2, vv = c1 & c2;
        u64 s3 = u ^ C,   w  = u & C;
        u64 t3 = vv | w;

        // plane1 += s3 + g0  (full add; carry = maj(p1,s3,g0))
        u64 t  = s3 ^ g0;
        u64 g1 = (p1 & t) | (s3 & g0);
        p1 ^= t;

        // plane2 += t3 + g1  (full add)
        u64 t2 = t3 ^ g1;
        u64 g2 = (p2 & t2) | (t3 & g1);
        p2 ^= t2;

        // ripple weights 8..128 (count <= 128 -> no overflow past p7)
        u64 g3 = p3 & g2; p3 ^= g2;
        u64 g4 = p4 & g3; p4 ^= g3;
        u64 g5 = p5 & g4; p5 ^= g4;
        u64 g6 = p6 & g5; p6 ^= g5;
        p7 ^= g6;
    }

    // Flush: wave-sum per bin via ballot+popcount of each plane's bit.
    // ws is wave-uniform (SGPR math); lane bb keeps bin bb's wave total.
    unsigned mycnt = 0;
#pragma unroll
    for (int bb = 0; bb < NBINS; ++bb) {
        unsigned ws =
              (unsigned)__popcll(__ballot((unsigned)((p0 >> bb) & 1ull)))
            + ((unsigned)__popcll(__ballot((unsigned)((p1 >> bb) & 1ull))) << 1)
            + ((unsigned)__popcll(__ballot((unsigned)((p2 >> bb) & 1ull))) << 2)
            + ((unsigned)__popcll(__ballot((unsigned)((p3 >> bb) & 1ull))) << 3)
            + ((unsigned)__popcll(__ballot((unsigned)((p4 >> bb) & 1ull))) << 4)
            + ((unsigned)__popcll(__ballot((unsigned)((p5 >> bb) & 1ull))) << 5)
            + ((unsigned)__popcll(__ballot((unsigned)((p6 >> bb) & 1ull))) << 6)
            + ((unsigned)__popcll(__ballot((unsigned)((p7 >> bb) & 1ull))) << 7);
        if (lane == bb) mycnt = ws;
    }
    // One LDS atomic per lane per wave for the entire kernel.
    atomicAdd(&bhist[lane], mycnt);
    __syncthreads();

    if (tid < NBINS)
        partial[(size_t)b * NBINS + tid] = bhist[tid];   // plain store
}

__global__ __launch_bounds__(1024)
void loss_kernel(const unsigned int* __restrict__ partial,
                 float* __restrict__ out) {
    const int tid = threadIdx.x;
    int acc = 0;
#pragma unroll
    for (int q = 0; q < 6; ++q) {
        const int pIdx = q * 1024 + tid;     // 0..6143
        const int r  = pIdx >> 6;
        const int bb = pIdx & 63;
        unsigned cf = 0, cr = 0;
#pragma unroll
        for (int c = 0; c < BPR; ++c) {
            cf += partial[((r * BPR + c) * NBINS) + bb];
            cr += partial[(((ROWS + r) * BPR + c) * NBINS) + bb];
        }
        int d = (int)cf - (int)cr;
        acc += (d < 0) ? -d : d;
    }
#pragma unroll
    for (int off = 32; off > 0; off >>= 1)
        acc += __shfl_down(acc, off, 64);
    __shared__ int wsum[16];
    if ((tid & 63) == 0) wsum[tid >> 6] = acc;
    __syncthreads();
    if (tid == 0) {
        long long total = 0;
#pragma unroll
        for (int k = 0; k < 16; ++k) total += wsum[k];
        out[0] = (float)((double)total / (262144.0 * 6144.0));
    }
}

extern "C" void kernel_launch(void* const* d_in, const int* in_sizes, int n_in,
                              void* d_out, int out_size, void* d_ws, size_t ws_size,
                              hipStream_t stream) {
    const float* fake = (const float*)d_in[0];
    const float* real = (const float*)d_in[1];
    unsigned int* partial = (unsigned int*)d_ws;  // 1536*64 u32 = 393216 B
    float* out = (float*)d_out;

    hist_kernel<<<NBLOCKS, THREADS, 0, stream>>>(fake, real, partial);
    loss_kernel<<<1, 1024, 0, stream>>>(partial, out);
}

// Round 2
// 228.513 us; speedup vs baseline: 1.0002x; 1.0002x over previous
//
#include <hip/hip_runtime.h>

// HistogramLoss: two [32,3,512,512] fp32 inputs, per-(B,C) 64-bin histogram
// over [0,1], row-normalized (row count exactly 2^18), L1 mean of diff.
//
// R7: R6's bit-sliced CSA was right (bank conflicts 0, DS wall gone) but
// ran latency-stalled: VGPR_Count=32 left no registers to hoist loads, so
// each iteration waited ~600-900cy on its own float4 (VALUBusy 38%, dur
// identical on L3-warm replays -> latency-bound, not BW). Fixes:
//  (1) explicit depth-4 software pipeline (named c0..c3/n0..n3 regs) +
//      __launch_bounds__(256,3) so the allocator may use ~96 VGPRs;
//  (2) BPR 8->4: 256 elems/thread amortizes the fixed ~1200-instr flush
//      (was 42% of main-loop work); 9th plane keeps capacity 511 >= 256
//      -> still provably exact integer counting;
//  (3) loss kernel parallelized: 24 blocks + 64-thread finisher (plain
//      stores, deterministic) instead of one 1024-thread block.

#define HW        262144             // 512*512 = 2^18
#define ROWS      96                 // B*C per image
#define NBINS     64
#define BPR       4                  // blocks per row
#define CHUNK     (HW / BPR)         // 65536 elements per block
#define THREADS   256
#define F4_ITERS  (CHUNK / 4 / THREADS)  // 64 float4 per thread -> 256 elems
#define NBLOCKS   (2 * ROWS * BPR)   // 768 (3 blocks/CU)

typedef unsigned long long u64;

// 4:2 carry-save compress four one-hot u64s into 9 bit-planes p0..p8.
// Planes: bit bb of pk = bit k of this thread's count for bin bb.
#define PROC4(v) do {                                                   \
    int b0 = min((int)((v).x * 64.0f), 63);                             \
    int b1 = min((int)((v).y * 64.0f), 63);                             \
    int b2 = min((int)((v).z * 64.0f), 63);                             \
    int b3 = min((int)((v).w * 64.0f), 63);                             \
    u64 m0 = 1ull << b0, m1 = 1ull << b1;                               \
    u64 m2 = 1ull << b2, m3 = 1ull << b3;                               \
    u64 s1 = m0 ^ m1, c1 = m0 & m1;                                     \
    u64 s2 = m2 ^ m3, c2 = m2 & m3;                                     \
    u64 S  = s1 ^ s2, C  = s1 & s2;                                     \
    u64 g0 = p0 & S;  p0 ^= S;                                          \
    u64 u  = c1 ^ c2, vv = c1 & c2;                                     \
    u64 s3 = u ^ C,   w  = u & C;                                       \
    u64 t3 = vv | w;                                                    \
    u64 t  = s3 ^ g0;                                                   \
    u64 g1 = (p1 & t) | (s3 & g0);  p1 ^= t;                            \
    u64 t2 = t3 ^ g1;                                                   \
    u64 g2 = (p2 & t2) | (t3 & g1); p2 ^= t2;                           \
    u64 g3 = p3 & g2; p3 ^= g2;                                         \
    u64 g4 = p4 & g3; p4 ^= g3;                                         \
    u64 g5 = p5 & g4; p5 ^= g4;                                         \
    u64 g6 = p6 & g5; p6 ^= g5;                                         \
    u64 g7 = p7 & g6; p7 ^= g6;                                         \
    p8 ^= g7;                                                           \
} while (0)

__global__ __launch_bounds__(THREADS, 3)
void hist_kernel(const float* __restrict__ fake,
                 const float* __restrict__ real,
                 unsigned int* __restrict__ partial) {
    __shared__ unsigned int bhist[NBINS];

    const int tid  = threadIdx.x;
    const int lane = tid & 63;

    if (tid < NBINS) bhist[tid] = 0u;
    __syncthreads();

    const int b     = blockIdx.x;          // 0 .. 767
    const int chunk = b & (BPR - 1);
    const int rowg  = b >> 2;              // 0..191: img*ROWS + row
    const float* src = (rowg < ROWS) ? fake : real;
    const int row    = (rowg < ROWS) ? rowg : (rowg - ROWS);

    const float4* __restrict__ q =
        (const float4*)(src + (size_t)row * HW + (size_t)chunk * CHUNK) + tid;

    u64 p0 = 0, p1 = 0, p2 = 0, p3 = 0, p4 = 0, p5 = 0, p6 = 0, p7 = 0, p8 = 0;

    // Depth-4 software pipeline: next group's loads issue before current
    // group's ~680cy of CSA compute -> HBM/L3 latency fully hidden.
    float4 c0 = q[0 * THREADS];
    float4 c1 = q[1 * THREADS];
    float4 c2 = q[2 * THREADS];
    float4 c3 = q[3 * THREADS];
    for (int i = 4; i < F4_ITERS; i += 4) {
        float4 n0 = q[(i + 0) * THREADS];
        float4 n1 = q[(i + 1) * THREADS];
        float4 n2 = q[(i + 2) * THREADS];
        float4 n3 = q[(i + 3) * THREADS];
        PROC4(c0); PROC4(c1); PROC4(c2); PROC4(c3);
        c0 = n0; c1 = n1; c2 = n2; c3 = n3;
    }
    PROC4(c0); PROC4(c1); PROC4(c2); PROC4(c3);

    // Flush: wave-sum per bin via ballot+popcount of each plane's bit.
    unsigned mycnt = 0;
#pragma unroll
    for (int bb = 0; bb < NBINS; ++bb) {
        unsigned ws =
              (unsigned)__popcll(__ballot((unsigned)((p0 >> bb) & 1ull)))
            + ((unsigned)__popcll(__ballot((unsigned)((p1 >> bb) & 1ull))) << 1)
            + ((unsigned)__popcll(__ballot((unsigned)((p2 >> bb) & 1ull))) << 2)
            + ((unsigned)__popcll(__ballot((unsigned)((p3 >> bb) & 1ull))) << 3)
            + ((unsigned)__popcll(__ballot((unsigned)((p4 >> bb) & 1ull))) << 4)
            + ((unsigned)__popcll(__ballot((unsigned)((p5 >> bb) & 1ull))) << 5)
            + ((unsigned)__popcll(__ballot((unsigned)((p6 >> bb) & 1ull))) << 6)
            + ((unsigned)__popcll(__ballot((unsigned)((p7 >> bb) & 1ull))) << 7)
            + ((unsigned)__popcll(__ballot((unsigned)((p8 >> bb) & 1ull))) << 8);
        if (lane == bb) mycnt = ws;
    }
    // One LDS atomic per lane per wave for the entire kernel.
    atomicAdd(&bhist[lane], mycnt);
    __syncthreads();

    if (tid < NBINS)
        partial[(size_t)b * NBINS + tid] = bhist[tid];   // plain store
}

// Stage 1: 24 blocks x 256 threads; each thread owns one (row,bin) pair.
__global__ __launch_bounds__(256)
void loss1_kernel(const unsigned int* __restrict__ partial,
                  unsigned int* __restrict__ blocksum) {
    const int tid = threadIdx.x;
    const int g   = blockIdx.x * 256 + tid;   // 0..6143
    const int r   = g >> 6;
    const int bb  = g & 63;
    unsigned cf = 0, cr = 0;
#pragma unroll
    for (int c = 0; c < BPR; ++c) {
        cf += partial[((r * BPR + c) * NBINS) + bb];
        cr += partial[(((ROWS + r) * BPR + c) * NBINS) + bb];
    }
    int d = (int)cf - (int)cr;
    int a = (d < 0) ? -d : d;
#pragma unroll
    for (int off = 32; off > 0; off >>= 1)
        a += __shfl_down(a, off, 64);
    __shared__ int wsum[4];
    if ((tid & 63) == 0) wsum[tid >> 6] = a;
    __syncthreads();
    if (tid == 0)
        blocksum[blockIdx.x] = (unsigned)(wsum[0] + wsum[1] + wsum[2] + wsum[3]);
}

// Stage 2: one wave folds the 24 block sums.
__global__ __launch_bounds__(64)
void loss2_kernel(const unsigned int* __restrict__ blocksum,
                  float* __restrict__ out) {
    const int lane = threadIdx.x;
    int a = (lane < 24) ? (int)blocksum[lane] : 0;
#pragma unroll
    for (int off = 32; off > 0; off >>= 1)
        a += __shfl_down(a, off, 64);
    if (lane == 0)
        out[0] = (float)((double)a / (262144.0 * 6144.0));
}

extern "C" void kernel_launch(void* const* d_in, const int* in_sizes, int n_in,
                              void* d_out, int out_size, void* d_ws, size_t ws_size,
                              hipStream_t stream) {
    const float* fake = (const float*)d_in[0];
    const float* real = (const float*)d_in[1];
    unsigned int* partial  = (unsigned int*)d_ws;            // 768*64 u32 = 196608 B
    unsigned int* blocksum = partial + NBLOCKS * NBINS;      // 24 u32
    float* out = (float*)d_out;

    hist_kernel<<<NBLOCKS, THREADS, 0, stream>>>(fake, real, partial);
    loss1_kernel<<<24, 256, 0, stream>>>(partial, blocksum);
    loss2_kernel<<<1, 64, 0, stream>>>(blocksum, out);
}